// Round 1
// baseline (3838.020 us; speedup 1.0000x reference)
//
#include <hip/hip_runtime.h>
#include <stdint.h>

#define GG 4
#define SS 512
#define HH 2048
#define VV 151936
#define MM (GG*SS)        // 2048 rows
#define BM 128
#define BN 128
#define BK 64
#define NV (VV/BN)        // 1187 v-tiles
#define QW 64             // workgroups along V per mtile
#define NMT (MM/BM)       // 16 mtiles

typedef __attribute__((ext_vector_type(8))) short v8s;
typedef __attribute__((ext_vector_type(4))) float v4f;

__device__ __forceinline__ unsigned short f2bf(float f){
  unsigned int u = __float_as_uint(f);
  return (unsigned short)((u + 0x7FFFu + ((u >> 16) & 1u)) >> 16);  // RNE
}

__global__ void cvt_kernel(const float* __restrict__ src, unsigned short* __restrict__ dst, long n4){
  long i = (long)blockIdx.x * blockDim.x + threadIdx.x;
  long stride = (long)gridDim.x * blockDim.x;
  for (; i < n4; i += stride){
    float4 v = ((const float4*)src)[i];
    short4 o;
    o.x = (short)f2bf(v.x); o.y = (short)f2bf(v.y);
    o.z = (short)f2bf(v.z); o.w = (short)f2bf(v.w);
    ((short4*)dst)[i] = o;
  }
}

// Fused GEMM + online (max, sum-exp) over V. Each workgroup: one 128-row mtile,
// v-tiles vt = q + 64*t. Running per-row softmax state in registers; one
// float2 partial per (row, q) at the end.
template<bool PRE>
__global__ __launch_bounds__(256, 2)
void gemm_lse(const float* __restrict__ Af, const float* __restrict__ Wf,
              const unsigned short* __restrict__ Ab, const unsigned short* __restrict__ Wb,
              float2* __restrict__ partials)
{
  __shared__ unsigned short Asm[BM*BK];
  __shared__ unsigned short Bsm[BN*BK];
  __shared__ float2 mbuf[2][2][64];

  const int t = threadIdx.x;
  const int mt = blockIdx.x;       // 0..15
  const int q  = blockIdx.y;       // 0..63
  const int wid = t >> 6, l = t & 63;
  const int wr = wid >> 1, wc = wid & 1;
  const int lr = l & 15, hi = l >> 4;
  const int mbase = mt * BM;

  float runM[4][4], runS[4][4];
  #pragma unroll
  for (int i=0;i<4;i++)
    #pragma unroll
    for (int r=0;r<4;r++){ runM[i][r] = -3.0e38f; runS[i][r] = 0.f; }

  for (int vt = q; vt < NV; vt += QW){
    const int nbase = vt * BN;
    v4f acc[4][4];
    #pragma unroll
    for (int i=0;i<4;i++)
      #pragma unroll
      for (int j=0;j<4;j++) acc[i][j] = (v4f){0.f,0.f,0.f,0.f};

    for (int kk = 0; kk < HH; kk += BK){
      __syncthreads();
      if constexpr (PRE){
        const unsigned short* ga = Ab + (size_t)mbase * HH + kk;
        const unsigned short* gb = Wb + (size_t)nbase * HH + kk;
        #pragma unroll
        for (int a=0;a<4;a++){
          int f = a*2048 + t*8;
          int row = f >> 6, col = f & 63;
          *(int4*)(Asm + f) = *(const int4*)(ga + (size_t)row*HH + col);
        }
        #pragma unroll
        for (int a=0;a<4;a++){
          int f = a*2048 + t*8;
          int row = f >> 6, col = f & 63;
          *(int4*)(Bsm + f) = *(const int4*)(gb + (size_t)row*HH + col);
        }
      } else {
        const float* ga = Af + (size_t)mbase * HH + kk;
        const float* gb = Wf + (size_t)nbase * HH + kk;
        #pragma unroll
        for (int a=0;a<8;a++){
          int f = a*1024 + t*4;
          int row = f >> 6, col = f & 63;
          float4 v = *(const float4*)(ga + (size_t)row*HH + col);
          short4 o; o.x=(short)f2bf(v.x); o.y=(short)f2bf(v.y);
          o.z=(short)f2bf(v.z); o.w=(short)f2bf(v.w);
          *(short4*)(Asm + f) = o;
        }
        #pragma unroll
        for (int a=0;a<8;a++){
          int f = a*1024 + t*4;
          int row = f >> 6, col = f & 63;
          float4 v = *(const float4*)(gb + (size_t)row*HH + col);
          short4 o; o.x=(short)f2bf(v.x); o.y=(short)f2bf(v.y);
          o.z=(short)f2bf(v.z); o.w=(short)f2bf(v.w);
          *(short4*)(Bsm + f) = o;
        }
      }
      __syncthreads();
      #pragma unroll
      for (int ks=0; ks<2; ks++){
        v8s afr[4], bfr[4];
        #pragma unroll
        for (int i=0;i<4;i++)
          afr[i] = *(const v8s*)(Asm + (wr*64 + i*16 + lr)*BK + ks*32 + hi*8);
        #pragma unroll
        for (int j=0;j<4;j++)
          bfr[j] = *(const v8s*)(Bsm + (wc*64 + j*16 + lr)*BK + ks*32 + hi*8);
        #pragma unroll
        for (int i=0;i<4;i++)
          #pragma unroll
          for (int j=0;j<4;j++)
            acc[i][j] = __builtin_amdgcn_mfma_f32_16x16x32_bf16(afr[i], bfr[j], acc[i][j], 0,0,0);
      }
    }

    // Epilogue: per-row max & sum-exp over this 128-col tile.
    // C layout: row = (l>>4)*4 + reg, col = l&15 (within 16x16 block).
    float tm[4][4], ts[4][4];
    #pragma unroll
    for (int i=0;i<4;i++){
      #pragma unroll
      for (int r=0;r<4;r++){
        float m = fmaxf(fmaxf(acc[i][0][r], acc[i][1][r]), fmaxf(acc[i][2][r], acc[i][3][r]));
        #pragma unroll
        for (int d=1; d<16; d<<=1) m = fmaxf(m, __shfl_xor(m, d));
        float s = 0.f;
        #pragma unroll
        for (int j=0;j<4;j++) s += __expf(acc[i][j][r] - m);
        #pragma unroll
        for (int d=1; d<16; d<<=1) s += __shfl_xor(s, d);
        tm[i][r] = m; ts[i][r] = s;
      }
    }
    if (lr == 0){
      #pragma unroll
      for (int i=0;i<4;i++)
        #pragma unroll
        for (int r=0;r<4;r++)
          mbuf[wr][wc][i*16 + hi*4 + r] = make_float2(tm[i][r], ts[i][r]);
    }
    __syncthreads();
    #pragma unroll
    for (int i=0;i<4;i++){
      #pragma unroll
      for (int r=0;r<4;r++){
        int rl = i*16 + hi*4 + r;
        float2 p0 = mbuf[wr][0][rl];
        float2 p1 = mbuf[wr][1][rl];
        float mm = fmaxf(p0.x, p1.x);
        float ss = p0.y * __expf(p0.x - mm) + p1.y * __expf(p1.x - mm);
        float Mn = fmaxf(runM[i][r], mm);
        runS[i][r] = runS[i][r] * __expf(runM[i][r] - Mn) + ss * __expf(mm - Mn);
        runM[i][r] = Mn;
      }
    }
  }

  if (wc == 0 && lr == 0){
    #pragma unroll
    for (int i=0;i<4;i++)
      #pragma unroll
      for (int r=0;r<4;r++){
        int row = mbase + wr*64 + i*16 + hi*4 + r;
        partials[(size_t)row * QW + q] = make_float2(runM[i][r], runS[i][r]);
      }
  }
}

// One block per row: exact fp32 label-logit dot + merge 64 partials -> token loss.
__global__ void finalize_rows(const float* __restrict__ A, const float* __restrict__ W,
                              const int* __restrict__ ids, const float* __restrict__ amask,
                              const float2* __restrict__ partials, float* __restrict__ tloss)
{
  const int row = blockIdx.x;
  const int t = threadIdx.x;
  const int g = row >> 9, s = row & (SS-1);
  const bool valid = (s < SS-1);
  const int lbl = valid ? ids[g*SS + s + 1] : 0;

  __shared__ float red[4];
  float acc = 0.f;
  #pragma unroll
  for (int it=0; it<2; it++){
    int k = (it*256 + t) * 4;
    float4 a = *(const float4*)(A + (size_t)row*HH + k);
    float4 w = *(const float4*)(W + (size_t)lbl*HH + k);
    acc += a.x*w.x + a.y*w.y + a.z*w.z + a.w*w.w;
  }
  #pragma unroll
  for (int d=1; d<64; d<<=1) acc += __shfl_xor(acc, d);
  if ((t & 63) == 0) red[t >> 6] = acc;
  __syncthreads();
  if (t < 64){
    float2 p = partials[(size_t)row * QW + t];
    float m = p.x, ssum = p.y;
    #pragma unroll
    for (int d=1; d<64; d<<=1){
      float om = __shfl_xor(m, d);
      float os = __shfl_xor(ssum, d);
      float Mn = fmaxf(m, om);
      ssum = ssum * __expf(m - Mn) + os * __expf(om - Mn);
      m = Mn;
    }
    if (t == 0){
      float lse = m + logf(ssum);
      float dot = red[0] + red[1] + red[2] + red[3];
      float msk = valid ? amask[g*SS + s + 1] : 0.f;
      tloss[row] = (lse - dot) * msk;
    }
  }
}

__global__ void final_reduce(const float* __restrict__ tloss, const float* __restrict__ amask,
                             const float* __restrict__ adv, float* __restrict__ out)
{
  const int t = threadIdx.x;
  const int g = t >> 6, lane = t & 63;
  float sl = 0.f, sm = 0.f;
  for (int s = lane; s < SS-1; s += 64){
    sl += tloss[g*SS + s];
    sm += amask[g*SS + s + 1];
  }
  #pragma unroll
  for (int d=1; d<64; d<<=1){ sl += __shfl_xor(sl, d); sm += __shfl_xor(sm, d); }
  __shared__ float red[4];
  if (lane == 0) red[g] = sl / fmaxf(sm, 1.0f) * adv[g];
  __syncthreads();
  if (t == 0) out[0] = (red[0] + red[1] + red[2] + red[3]) * 0.25f;
}

extern "C" void kernel_launch(void* const* d_in, const int* in_sizes, int n_in,
                              void* d_out, int out_size, void* d_ws, size_t ws_size,
                              hipStream_t stream)
{
  const float* hidden = (const float*)d_in[0];
  const float* W      = (const float*)d_in[1];
  const int*   ids    = (const int*)d_in[2];
  const float* amask  = (const float*)d_in[3];
  const float* adv    = (const float*)d_in[4];
  float* out = (float*)d_out;

  const size_t abytes = (size_t)MM*HH*2;               // 8 MB  (A as bf16)
  const size_t wbytes = (size_t)VV*HH*2;               // 622 MB (W as bf16)
  const size_t pbytes = (size_t)MM*QW*sizeof(float2);  // 1 MB partials
  const size_t tbytes = (size_t)MM*sizeof(float);      // token losses
  const size_t need_pre = abytes + wbytes + pbytes + tbytes;

  if (ws_size >= need_pre){
    unsigned short* Ab = (unsigned short*)d_ws;
    unsigned short* Wb = (unsigned short*)((char*)d_ws + abytes);
    float2* partials = (float2*)((char*)d_ws + abytes + wbytes);
    float* tloss = (float*)((char*)d_ws + abytes + wbytes + pbytes);
    cvt_kernel<<<4096, 256, 0, stream>>>(hidden, Ab, (long)(((size_t)MM*HH)/4));
    cvt_kernel<<<8192, 256, 0, stream>>>(W, Wb, (long)(((size_t)VV*HH)/4));
    gemm_lse<true><<<dim3(NMT, QW), 256, 0, stream>>>(hidden, W, Ab, Wb, partials);
    finalize_rows<<<MM, 256, 0, stream>>>(hidden, W, ids, amask, partials, tloss);
    final_reduce<<<1, 256, 0, stream>>>(tloss, amask, adv, out);
  } else {
    float2* partials = (float2*)d_ws;
    float* tloss = (float*)((char*)d_ws + pbytes);
    gemm_lse<false><<<dim3(NMT, QW), 256, 0, stream>>>(hidden, W, nullptr, nullptr, partials);
    finalize_rows<<<MM, 256, 0, stream>>>(hidden, W, ids, amask, partials, tloss);
    final_reduce<<<1, 256, 0, stream>>>(tloss, amask, adv, out);
  }
}